// Round 6
// baseline (1533.227 us; speedup 1.0000x reference)
//
#include <hip/hip_runtime.h>

#define T_ 96
#define N_ 1140
#define F_ 64
#define H_ 32
#define E_ 22800
#define LH_ 250
#define G4_ 1000
#define OUT_ 2280
#define KIN_ 36480   // N_*H_
#define SPLITK 30
#define KC 32
#define BN 32

typedef _Float16 h2_t __attribute__((ext_vector_type(2)));
typedef unsigned long long u64;

__device__ __forceinline__ float leaky02(float x){ return x > 0.f ? x : 0.2f*x; }
__device__ __forceinline__ float fsigm(float x){ return 1.f/(1.f + __expf(-x)); }
__device__ __forceinline__ float ftanh(float x){
  x = fminf(fmaxf(x, -15.f), 15.f);
  float t = __expf(2.f * x);
  return (t - 1.f) / (t + 1.f);
}
__device__ __forceinline__ unsigned packh2(float a, float b) {
  auto p = __builtin_amdgcn_cvt_pkrtz(a, b);   // __fp16 ext_vector(2)
  return __builtin_bit_cast(unsigned, p);
}
__device__ __forceinline__ float fdot2u(unsigned w, unsigned h, float acc) {
  return __builtin_amdgcn_fdot2(__builtin_bit_cast(h2_t, w),
                                __builtin_bit_cast(h2_t, h), acc, false);
}

// tagged-word publish: RMW executes at the coherence point (L3) -> prompt
// visibility; readers use relaxed sc1 loads.
__device__ __forceinline__ void post64(u64* p, u64 v) {
  (void)__hip_atomic_exchange(p, v, __ATOMIC_RELAXED, __HIP_MEMORY_SCOPE_AGENT);
}
__device__ __forceinline__ u64 ld64a(const u64* p) {
  return __hip_atomic_load((u64*)p, __ATOMIC_RELAXED, __HIP_MEMORY_SCOPE_AGENT);
}

// ---------------- GAT feature transform: H = x@W, HS = H@a_s, HD = H@a_d ----
__global__ void k_feat(const float* __restrict__ x, const float* __restrict__ W,
                       const float* __restrict__ as_, const float* __restrict__ ad_,
                       float* __restrict__ Hout, float* __restrict__ HS,
                       float* __restrict__ HD, int K) {
  int gid = blockIdx.x * blockDim.x + threadIdx.x;
  int row = gid >> 5; int c = gid & 31;
  if (row >= T_ * N_) return;
  const float* xr = x + (size_t)row * K;
  float acc = 0.f;
  for (int k = 0; k < K; ++k) acc += xr[k] * W[k * H_ + c];
  Hout[(size_t)row * H_ + c] = acc;
  float ps = acc * as_[c], pd = acc * ad_[c];
  #pragma unroll
  for (int off = 16; off > 0; off >>= 1) {
    ps += __shfl_xor(ps, off, 32);
    pd += __shfl_xor(pd, off, 32);
  }
  if (c == 0) { HS[row] = ps; HD[row] = pd; }
}

// ---------------- CSR build ------------------------------------------------
__global__ void k_count(const int* __restrict__ ei, int* __restrict__ counts) {
  int gid = blockIdx.x * blockDim.x + threadIdx.x;
  if (gid >= T_ * E_) return;
  int t = gid / E_; int k = gid - t * E_;
  int dst = ei[(size_t)t * 2 * E_ + E_ + k];
  atomicAdd(&counts[t * N_ + dst], 1);
}

__global__ void k_scan(const int* __restrict__ counts, int* __restrict__ offs,
                       int* __restrict__ cursor) {
  int t = blockIdx.x; int tid = threadIdx.x;
  int base = tid * 5;
  int v[5]; int s = 0;
  #pragma unroll
  for (int r = 0; r < 5; ++r) {
    int i = base + r;
    int c = (i < N_) ? counts[t * N_ + i] : 0;
    v[r] = c; s += c;
  }
  __shared__ int sh[256];
  sh[tid] = s; __syncthreads();
  for (int off = 1; off < 256; off <<= 1) {
    int add = (tid >= off) ? sh[tid - off] : 0;
    __syncthreads();
    sh[tid] += add;
    __syncthreads();
  }
  int run = sh[tid] - s;  // exclusive prefix of this thread's chunk
  #pragma unroll
  for (int r = 0; r < 5; ++r) {
    int i = base + r;
    if (i < N_) { offs[t * (N_ + 1) + i] = run; cursor[t * N_ + i] = run; }
    run += v[r];
  }
  if (tid == 255) offs[t * (N_ + 1) + N_] = sh[255];
}

__global__ void k_fill(const int* __restrict__ ei, int* __restrict__ cursor,
                       int* __restrict__ elist) {
  int gid = blockIdx.x * blockDim.x + threadIdx.x;
  if (gid >= T_ * E_) return;
  int t = gid / E_; int k = gid - t * E_;
  int src = ei[(size_t)t * 2 * E_ + k];
  int dst = ei[(size_t)t * 2 * E_ + E_ + k];
  int pos = atomicAdd(&cursor[t * N_ + dst], 1);
  elist[(size_t)t * E_ + pos] = src;
}

// ---------------- GAT attention aggregate (online softmax per dst) ---------
__global__ void k_aggr(const float* __restrict__ Hf, const float* __restrict__ HS,
                       const float* __restrict__ HD, const int* __restrict__ offs,
                       const int* __restrict__ elist, const float* __restrict__ b,
                       float* __restrict__ Xout, int relu) {
  int gid = blockIdx.x * blockDim.x + threadIdx.x;
  int row = gid >> 5; int c = gid & 31;
  if (row >= T_ * N_) return;
  int t = row / N_; int i = row - t * N_;
  float hd_i = HD[row];
  float m = leaky02(HS[row] + hd_i);   // self-loop
  float s = 1.f;
  float acc = Hf[(size_t)row * H_ + c];
  int e0 = offs[t * (N_ + 1) + i], e1 = offs[t * (N_ + 1) + i + 1];
  const int* el = elist + (size_t)t * E_;
  const float* Ht = Hf + (size_t)t * N_ * H_;
  const float* HSt = HS + t * N_;
  for (int e = e0; e < e1; ++e) {
    int src = el[e];
    float eg = leaky02(HSt[src] + hd_i);
    float mn = fmaxf(m, eg);
    float scl = __expf(m - mn);
    float p = __expf(eg - mn);
    s = s * scl + p;
    acc = acc * scl + p * Ht[(size_t)src * H_ + c];
    m = mn;
  }
  float val = acc / s + b[c];
  if (relu) val = fmaxf(val, 0.f);
  Xout[(size_t)row * H_ + c] = val;
}

// ------- LSTM0 input GEMM (f16 dot2): (96 x 36480) @ (36480 x 1000)^T ------
__global__ void k_gemm(const float* __restrict__ X, const float* __restrict__ Wih,
                       float* __restrict__ Gpart) {
  __shared__ unsigned Xs[T_][KC / 2 + 1];   // f16 pairs along K
  __shared__ unsigned Ws[BN][KC / 2 + 1];
  int j0 = blockIdx.x * BN;
  int sp = blockIdx.y;
  int tid = threadIdx.x;
  int jj = tid & 7;    // 8 j-groups of 4
  int tt = tid >> 3;   // 16 t-groups of 6
  float acc[6][4] = {};
  int kbeg = sp * (KIN_ / SPLITK);
  int kend = kbeg + (KIN_ / SPLITK);
  for (int k0 = kbeg; k0 < kend; k0 += KC) {
    for (int idx = tid; idx < T_ * (KC / 2); idx += 128) {
      int tr = idx >> 4; int kk = idx & 15;
      const float2 v = *(const float2*)(X + (size_t)tr * KIN_ + k0 + 2 * kk);
      Xs[tr][kk] = packh2(v.x, v.y);
    }
    for (int idx = tid; idx < BN * (KC / 2); idx += 128) {
      int jr = idx >> 4; int kk = idx & 15;
      int j = j0 + jr;
      unsigned v = 0;
      if (j < G4_) {
        const float2 w = *(const float2*)(Wih + (size_t)j * KIN_ + k0 + 2 * kk);
        v = packh2(w.x, w.y);
      }
      Ws[jr][kk] = v;
    }
    __syncthreads();
    for (int kk = 0; kk < KC / 2; ++kk) {
      unsigned xv[6], wv[4];
      #pragma unroll
      for (int r = 0; r < 6; ++r) xv[r] = Xs[tt * 6 + r][kk];
      #pragma unroll
      for (int q = 0; q < 4; ++q) wv[q] = Ws[jj * 4 + q][kk];
      #pragma unroll
      for (int r = 0; r < 6; ++r)
        #pragma unroll
        for (int q = 0; q < 4; ++q)
          acc[r][q] = fdot2u(wv[q], xv[r], acc[r][q]);
    }
    __syncthreads();
  }
  #pragma unroll
  for (int r = 0; r < 6; ++r) {
    int t = tt * 6 + r;
    #pragma unroll
    for (int q = 0; q < 4; ++q) {
      int j = j0 + jj * 4 + q;
      if (j < G4_) Gpart[((size_t)sp * T_ + t) * 1024 + j] = acc[r][q];
    }
  }
}

// G0 reduced with gate-interleaved layout: G0[t*1000 + j*4 + g]
__global__ void k_gred(const float* __restrict__ Gpart, const float* __restrict__ bih,
                       const float* __restrict__ bhh, float* __restrict__ G0) {
  int idx = blockIdx.x * blockDim.x + threadIdx.x;
  if (idx >= T_ * G4_) return;
  int t = idx / G4_; int jg = idx - t * G4_;
  int j = jg >> 2, g = jg & 3;
  int c = g * LH_ + j;                      // gate-major column in Gpart
  float s = bih[c] + bhh[c];
  for (int sp = 0; sp < SPLITK; ++sp) s += Gpart[((size_t)sp * T_ + t) * 1024 + c];
  G0[idx] = s;
}

// ------ tagged-dataflow 2-layer LSTM (no barriers, no flags) ---------------
// 64 waves across 8 WGs. Wave wv owns units 4wv..4wv+3. h exchanged as u64
// words {tag<<32 | f16pair}; writer = atomic swap (executes at L3); readers
// spin on relaxed loads until the tag matches.
// Ring parity (re-derived per region; R5 deadlock was reading h1 at the
// wrong parity):  h0[p] -> slot p&1, tag p+1, read at phase p+1 from slot
// (p+1-1)&1 = p&1.  h1[q-1] -> slot (q-1)&1, tag q, read at phase q+1 from
// slot (q+1)&1 = (q-1)&1.  Overwrites are gated: posting at phase p
// requires having swept all tag-p h0 words, and every wave posts its h0
// only AFTER completing its full sweep -> all reads of the data being
// overwritten have retired. Bounded spin = hang insurance only.
__global__ void __launch_bounds__(512, 2) k_lstm(
    const float* __restrict__ G0, const float* __restrict__ Whh0,
    const float* __restrict__ Wih1, const float* __restrict__ Whh1,
    const float* __restrict__ bih1, const float* __restrict__ bhh1,
    const float* __restrict__ h0in, const float* __restrict__ c0in,
    u64* __restrict__ hp,          // [2 slots][2 layers][128] tagged words
    float* __restrict__ ylast) {
  int tid = threadIdx.x;
  int wv = blockIdx.x * 8 + (tid >> 6);   // 0..63
  if (wv * 4 >= LH_) return;              // wave 63 idle
  int lane = tid & 63;
  int qg = lane >> 4;              // gate: 0=i 1=f 2=g 3=o
  int ql = lane & 15;

  unsigned w0[4][8], wx1[4][8], wh1[4][8];
  float bs1[4], c0l[4], c1l[4];
  bool act[4];
  #pragma unroll
  for (int u = 0; u < 4; ++u) {
    int U = wv * 4 + u;
    act[u] = (U < LH_);
    int Uc = act[u] ? U : 0;
    size_t rb = (size_t)(qg * LH_ + Uc) * LH_;
    #pragma unroll
    for (int m = 0; m < 8; ++m) {
      int pi = m * 16 + ql;
      if (act[u] && pi < 125) {
        w0[u][m]  = packh2(Whh0[rb + 2 * pi], Whh0[rb + 2 * pi + 1]);
        wx1[u][m] = packh2(Wih1[rb + 2 * pi], Wih1[rb + 2 * pi + 1]);
        wh1[u][m] = packh2(Whh1[rb + 2 * pi], Whh1[rb + 2 * pi + 1]);
      } else { w0[u][m] = 0; wx1[u][m] = 0; wh1[u][m] = 0; }
    }
    bs1[u] = act[u] ? (bih1[qg * LH_ + Uc] + bhh1[qg * LH_ + Uc]) : 0.f;
    c0l[u] = act[u] ? c0in[Uc] : 0.f;
    c1l[u] = act[u] ? c0in[LH_ + Uc] : 0.f;
  }

  // sweep mask: word m*16+ql exists iff < 125
  unsigned maskAll = 0;
  #pragma unroll
  for (int m = 0; m < 8; ++m) if (m * 16 + ql < 125) maskAll |= 1u << m;

  unsigned x0p[8], h1p[8];

  for (int p = 0; p <= T_; ++p) {
    // G0 preactivations for this phase: issue before the sweep (hides latency)
    float gpre[4];
    #pragma unroll
    for (int u = 0; u < 4; ++u)
      gpre[u] = (p < T_ && act[u]) ? G0[p * G4_ + (wv * 4 + u) * 4 + qg] : 0.f;

    if (p == 0) {
      #pragma unroll
      for (int m = 0; m < 8; ++m) {
        int pi = m * 16 + ql;
        x0p[m] = (pi < 125) ? packh2(h0in[2 * pi], h0in[2 * pi + 1]) : 0u;
      }
    } else {
      const u64* S0  = hp + (size_t)((p - 1) & 1) * 256;        // h0[p-1], tag p
      const u64* S1h = hp + (size_t)(p & 1) * 256 + 128;        // h1[p-2], tag p-1
      unsigned tx = (unsigned)p, th = (unsigned)(p - 1);
      unsigned needx = maskAll;
      unsigned needh = (p >= 2) ? maskAll : 0u;
      #pragma unroll
      for (int m = 0; m < 8; ++m) { x0p[m] = 0u; h1p[m] = 0u; }
      int guard = 0;
      while ((needx | needh) && ++guard < 16384) {
        #pragma unroll
        for (int m = 0; m < 8; ++m) {
          if (needx & (1u << m)) {
            u64 v = ld64a(&S0[m * 16 + ql]);
            if ((unsigned)(v >> 32) == tx) { x0p[m] = (unsigned)v; needx &= ~(1u << m); }
          }
          if (needh & (1u << m)) {
            u64 v = ld64a(&S1h[m * 16 + ql]);
            if ((unsigned)(v >> 32) == th) { h1p[m] = (unsigned)v; needh &= ~(1u << m); }
          }
        }
      }
      if (p == 1) {
        #pragma unroll
        for (int m = 0; m < 8; ++m) {
          int pi = m * 16 + ql;
          h1p[m] = (pi < 125) ? packh2(h0in[LH_ + 2 * pi], h0in[LH_ + 2 * pi + 1]) : 0u;
        }
      }
    }

    // ---- layer 0, step p ----
    if (p < T_) {
      float h0new[4];
      #pragma unroll
      for (int u = 0; u < 4; ++u) {
        float s = 0.f;
        #pragma unroll
        for (int m = 0; m < 8; ++m) s = fdot2u(w0[u][m], x0p[m], s);
        s += __shfl_xor(s, 1); s += __shfl_xor(s, 2);
        s += __shfl_xor(s, 4); s += __shfl_xor(s, 8);
        float pre = s + gpre[u];
        float a = (qg == 2) ? ftanh(pre) : fsigm(pre);
        float ai = __shfl(a, ql);
        float af = __shfl(a, 16 + ql);
        float ag = __shfl(a, 32 + ql);
        float ao = __shfl(a, 48 + ql);
        c0l[u] = af * c0l[u] + ai * ag;
        h0new[u] = act[u] ? (ao * ftanh(c0l[u])) : 0.f;
      }
      int w = 2 * wv + lane;   // lane 0 -> word 2wv, lane 1 -> word 2wv+1
      if (lane < 2 && w < 125) {
        unsigned pair = (lane == 0) ? packh2(h0new[0], h0new[1])
                                    : packh2(h0new[2], h0new[3]);
        post64(&hp[(size_t)(p & 1) * 256 + w], ((u64)(unsigned)(p + 1) << 32) | pair);
      }
    }
    // ---- layer 1, step p-1 ----
    if (p >= 1) {
      float h1new[4];
      #pragma unroll
      for (int u = 0; u < 4; ++u) {
        float s = 0.f;
        #pragma unroll
        for (int m = 0; m < 8; ++m) s = fdot2u(wx1[u][m], x0p[m], s);
        #pragma unroll
        for (int m = 0; m < 8; ++m) s = fdot2u(wh1[u][m], h1p[m], s);
        s += __shfl_xor(s, 1); s += __shfl_xor(s, 2);
        s += __shfl_xor(s, 4); s += __shfl_xor(s, 8);
        float pre = s + bs1[u];
        float a = (qg == 2) ? ftanh(pre) : fsigm(pre);
        float bi = __shfl(a, ql);
        float bf = __shfl(a, 16 + ql);
        float bg = __shfl(a, 32 + ql);
        float bo = __shfl(a, 48 + ql);
        c1l[u] = bf * c1l[u] + bi * bg;
        h1new[u] = act[u] ? (bo * ftanh(c1l[u])) : 0.f;
      }
      if (p - 1 == T_ - 1) {
        if (lane == 0) {
          #pragma unroll
          for (int u = 0; u < 4; ++u)
            if (act[u]) ylast[wv * 4 + u] = h1new[u];
        }
      } else {
        int w = 2 * wv + lane;
        if (lane < 2 && w < 125) {
          unsigned pair = (lane == 0) ? packh2(h1new[0], h1new[1])
                                      : packh2(h1new[2], h1new[3]);
          post64(&hp[(size_t)((p - 1) & 1) * 256 + 128 + w],
                 ((u64)(unsigned)p << 32) | pair);
        }
      }
    }
  }
}

// ---------------- 4 FC heads ----------------------------------------------
__global__ void k_fc(const float* __restrict__ ylast,
                     const float* __restrict__ Wa, const float* __restrict__ ba,
                     const float* __restrict__ Wb, const float* __restrict__ bb,
                     const float* __restrict__ Wc, const float* __restrict__ bc,
                     const float* __restrict__ Wd, const float* __restrict__ bd,
                     float* __restrict__ out) {
  int wg = blockIdx.x * 4 + (threadIdx.x >> 6);
  int lane = threadIdx.x & 63;
  if (wg >= 4 * OUT_) return;
  int head = wg / OUT_, o = wg - head * OUT_;
  const float* W = head == 0 ? Wa : head == 1 ? Wb : head == 2 ? Wc : Wd;
  const float* b = head == 0 ? ba : head == 1 ? bb : head == 2 ? bc : bd;
  float s = 0.f;
  #pragma unroll
  for (int r = 0; r < 4; ++r) {
    int idx = r * 64 + lane;
    if (idx < LH_) s += ylast[idx] * W[(size_t)o * LH_ + idx];
  }
  #pragma unroll
  for (int off = 32; off > 0; off >>= 1) s += __shfl_xor(s, off, 64);
  if (lane == 0) out[wg] = s + b[o];
}

// ---------------- launch ---------------------------------------------------
extern "C" void kernel_launch(void* const* d_in, const int* in_sizes, int n_in,
                              void* d_out, int out_size, void* d_ws, size_t ws_size,
                              hipStream_t stream) {
  const float* nodes = (const float*)d_in[0];
  const int*   ei    = (const int*)d_in[1];
  const float* W1    = (const float*)d_in[3];
  const float* as1   = (const float*)d_in[4];
  const float* ad1   = (const float*)d_in[5];
  const float* b1    = (const float*)d_in[6];
  const float* W2    = (const float*)d_in[7];
  const float* as2   = (const float*)d_in[8];
  const float* ad2   = (const float*)d_in[9];
  const float* b2    = (const float*)d_in[10];
  const float* Wih0  = (const float*)d_in[11];
  const float* Whh0  = (const float*)d_in[12];
  const float* bih0  = (const float*)d_in[13];
  const float* bhh0  = (const float*)d_in[14];
  const float* Wih1  = (const float*)d_in[15];
  const float* Whh1  = (const float*)d_in[16];
  const float* bih1  = (const float*)d_in[17];
  const float* bhh1  = (const float*)d_in[18];
  const float* h0    = (const float*)d_in[19];
  const float* c0    = (const float*)d_in[20];
  const float* fW1   = (const float*)d_in[21];
  const float* fb1   = (const float*)d_in[22];
  const float* fW2   = (const float*)d_in[23];
  const float* fb2   = (const float*)d_in[24];
  const float* fW3   = (const float*)d_in[25];
  const float* fb3   = (const float*)d_in[26];
  const float* fW4   = (const float*)d_in[27];
  const float* fb4   = (const float*)d_in[28];
  float* out = (float*)d_out;

  // workspace layout (bytes)
  const size_t o_H      = 0;
  const size_t o_HS     = 14008320;
  const size_t o_HD     = 14446080;
  const size_t o_X1     = 14883840;
  const size_t o_X2     = 28892160;
  const size_t o_counts = 42900480;
  const size_t o_offs   = 43338240;
  const size_t o_cursor = 43776512;
  const size_t o_elist  = 44214272;
  const size_t o_Gpart  = 52969472;
  const size_t o_G0     = 64765952;
  const size_t o_hp     = 65149952;   // 2*2*128 u64 = 4096 B
  const size_t o_ylast  = 65154048;   // 1024 B
  const size_t total    = 65155072;
  if (ws_size < total) return;  // leaves d_out poisoned -> visible failure

  char* ws = (char*)d_ws;
  float* Hbuf   = (float*)(ws + o_H);
  float* HS     = (float*)(ws + o_HS);
  float* HD     = (float*)(ws + o_HD);
  float* X1     = (float*)(ws + o_X1);
  float* X2     = (float*)(ws + o_X2);
  int*   counts = (int*)(ws + o_counts);
  int*   offs   = (int*)(ws + o_offs);
  int*   cursor = (int*)(ws + o_cursor);
  int*   elist  = (int*)(ws + o_elist);
  float* Gpart  = (float*)(ws + o_Gpart);
  float* G0     = (float*)(ws + o_G0);
  u64*   hp     = (u64*)(ws + o_hp);
  float* ylast  = (float*)(ws + o_ylast);

  (void)hipMemsetAsync(counts, 0, (size_t)T_ * N_ * 4, stream);
  (void)hipMemsetAsync(hp, 0, 4096, stream);

  const int rows_grid = (T_ * N_ * H_) / 256;   // 13680
  const int eg = (T_ * E_ + 255) / 256;         // 8550

  // GAT layer 1
  k_feat<<<rows_grid, 256, 0, stream>>>(nodes, W1, as1, ad1, Hbuf, HS, HD, F_);
  k_count<<<eg, 256, 0, stream>>>(ei, counts);
  k_scan<<<T_, 256, 0, stream>>>(counts, offs, cursor);
  k_fill<<<eg, 256, 0, stream>>>(ei, cursor, elist);
  k_aggr<<<rows_grid, 256, 0, stream>>>(Hbuf, HS, HD, offs, elist, b1, X1, 1);
  // GAT layer 2
  k_feat<<<rows_grid, 256, 0, stream>>>(X1, W2, as2, ad2, Hbuf, HS, HD, H_);
  k_aggr<<<rows_grid, 256, 0, stream>>>(Hbuf, HS, HD, offs, elist, b2, X2, 0);
  // LSTM0 input projection (f16 dot2)
  k_gemm<<<dim3(32, SPLITK), 128, 0, stream>>>(X2, Wih0, Gpart);
  k_gred<<<(T_ * G4_ + 255) / 256, 256, 0, stream>>>(Gpart, bih0, bhh0, G0);
  // tagged-dataflow recurrence (no barriers, parity-fixed)
  k_lstm<<<8, 512, 0, stream>>>(G0, Whh0, Wih1, Whh1, bih1, bhh1, h0, c0,
                                hp, ylast);
  // FC heads
  k_fc<<<OUT_, 256, 0, stream>>>(ylast, fW1, fb1, fW2, fb2, fW3, fb3, fW4, fb4, out);
}

// Round 8
// 1195.839 us; speedup vs baseline: 1.2821x; 1.2821x over previous
//
#include <hip/hip_runtime.h>

#define T_ 96
#define N_ 1140
#define F_ 64
#define H_ 32
#define E_ 22800
#define LH_ 250
#define G4_ 1000
#define OUT_ 2280
#define KIN_ 36480   // N_*H_
#define SPLITK 60
#define KC 32
#define BN 32

typedef _Float16 h2_t __attribute__((ext_vector_type(2)));

__device__ __forceinline__ float leaky02(float x){ return x > 0.f ? x : 0.2f*x; }
__device__ __forceinline__ float fsigm(float x){ return 1.f/(1.f + __expf(-x)); }
__device__ __forceinline__ float ftanh(float x){
  x = fminf(fmaxf(x, -15.f), 15.f);
  float t = __expf(2.f * x);
  return (t - 1.f) / (t + 1.f);
}
__device__ __forceinline__ unsigned packh2(float a, float b) {
  auto p = __builtin_amdgcn_cvt_pkrtz(a, b);   // __fp16 ext_vector(2)
  return __builtin_bit_cast(unsigned, p);
}
__device__ __forceinline__ float fdot2u(unsigned w, unsigned h, float acc) {
  return __builtin_amdgcn_fdot2(__builtin_bit_cast(h2_t, w),
                                __builtin_bit_cast(h2_t, h), acc, false);
}

// relaxed agent-scope atomics -> sc1 ops at the coherence point, no L2 wb/inv
__device__ __forceinline__ void st_agent_u(unsigned* p, unsigned v) {
  __hip_atomic_store(p, v, __ATOMIC_RELAXED, __HIP_MEMORY_SCOPE_AGENT);
}
__device__ __forceinline__ unsigned ld_agent_u(const unsigned* p) {
  return __hip_atomic_load((unsigned*)p, __ATOMIC_RELAXED, __HIP_MEMORY_SCOPE_AGENT);
}
__device__ __forceinline__ void st_agent_i(int* p, int v) {
  __hip_atomic_store(p, v, __ATOMIC_RELAXED, __HIP_MEMORY_SCOPE_AGENT);
}
__device__ __forceinline__ int ld_agent_i(const int* p) {
  return __hip_atomic_load((int*)p, __ATOMIC_RELAXED, __HIP_MEMORY_SCOPE_AGENT);
}

// ---------------- GAT feature transform: H = x@W, HS = H@a_s, HD = H@a_d ----
__global__ void k_feat(const float* __restrict__ x, const float* __restrict__ W,
                       const float* __restrict__ as_, const float* __restrict__ ad_,
                       float* __restrict__ Hout, float* __restrict__ HS,
                       float* __restrict__ HD, int K) {
  int gid = blockIdx.x * blockDim.x + threadIdx.x;
  int row = gid >> 5; int c = gid & 31;
  if (row >= T_ * N_) return;
  const float* xr = x + (size_t)row * K;
  float acc = 0.f;
  for (int k = 0; k < K; ++k) acc += xr[k] * W[k * H_ + c];
  Hout[(size_t)row * H_ + c] = acc;
  float ps = acc * as_[c], pd = acc * ad_[c];
  #pragma unroll
  for (int off = 16; off > 0; off >>= 1) {
    ps += __shfl_xor(ps, off, 32);
    pd += __shfl_xor(pd, off, 32);
  }
  if (c == 0) { HS[row] = ps; HD[row] = pd; }
}

// ---------------- CSR build ------------------------------------------------
__global__ void k_count(const int* __restrict__ ei, int* __restrict__ counts) {
  int gid = blockIdx.x * blockDim.x + threadIdx.x;
  if (gid >= T_ * E_) return;
  int t = gid / E_; int k = gid - t * E_;
  int dst = ei[(size_t)t * 2 * E_ + E_ + k];
  atomicAdd(&counts[t * N_ + dst], 1);
}

__global__ void k_scan(const int* __restrict__ counts, int* __restrict__ offs,
                       int* __restrict__ cursor) {
  int t = blockIdx.x; int tid = threadIdx.x;
  int base = tid * 5;
  int v[5]; int s = 0;
  #pragma unroll
  for (int r = 0; r < 5; ++r) {
    int i = base + r;
    int c = (i < N_) ? counts[t * N_ + i] : 0;
    v[r] = c; s += c;
  }
  __shared__ int sh[256];
  sh[tid] = s; __syncthreads();
  for (int off = 1; off < 256; off <<= 1) {
    int add = (tid >= off) ? sh[tid - off] : 0;
    __syncthreads();
    sh[tid] += add;
    __syncthreads();
  }
  int run = sh[tid] - s;  // exclusive prefix of this thread's chunk
  #pragma unroll
  for (int r = 0; r < 5; ++r) {
    int i = base + r;
    if (i < N_) { offs[t * (N_ + 1) + i] = run; cursor[t * N_ + i] = run; }
    run += v[r];
  }
  if (tid == 255) offs[t * (N_ + 1) + N_] = sh[255];
}

__global__ void k_fill(const int* __restrict__ ei, int* __restrict__ cursor,
                       int* __restrict__ elist) {
  int gid = blockIdx.x * blockDim.x + threadIdx.x;
  if (gid >= T_ * E_) return;
  int t = gid / E_; int k = gid - t * E_;
  int src = ei[(size_t)t * 2 * E_ + k];
  int dst = ei[(size_t)t * 2 * E_ + E_ + k];
  int pos = atomicAdd(&cursor[t * N_ + dst], 1);
  elist[(size_t)t * E_ + pos] = src;
}

// ---------------- GAT attention aggregate (online softmax per dst) ---------
// Software-pipelined edge loop: next edge's src/HS/H-row loads issue while
// the current edge's exp-chain computes -> load latency off the chain.
__global__ void k_aggr(const float* __restrict__ Hf, const float* __restrict__ HS,
                       const float* __restrict__ HD, const int* __restrict__ offs,
                       const int* __restrict__ elist, const float* __restrict__ b,
                       float* __restrict__ Xout, int relu) {
  int gid = blockIdx.x * blockDim.x + threadIdx.x;
  int row = gid >> 5; int c = gid & 31;
  if (row >= T_ * N_) return;
  int t = row / N_; int i = row - t * N_;
  float hd_i = HD[row];
  float m = leaky02(HS[row] + hd_i);   // self-loop
  float s = 1.f;
  float acc = Hf[(size_t)row * H_ + c];
  int e0 = offs[t * (N_ + 1) + i], e1 = offs[t * (N_ + 1) + i + 1];
  const int* el = elist + (size_t)t * E_;
  const float* Ht = Hf + (size_t)t * N_ * H_;
  const float* HSt = HS + t * N_;
  float hsA = 0.f, hvA = 0.f;
  if (e0 < e1) {
    int srcA = el[e0];
    hsA = HSt[srcA];
    hvA = Ht[(size_t)srcA * H_ + c];
  }
  for (int e = e0; e < e1; ++e) {
    float hs = hsA, hv = hvA;
    if (e + 1 < e1) {
      int srcA = el[e + 1];
      hsA = HSt[srcA];
      hvA = Ht[(size_t)srcA * H_ + c];
    }
    float eg = leaky02(hs + hd_i);
    float mn = fmaxf(m, eg);
    float scl = __expf(m - mn);
    float p = __expf(eg - mn);
    s = s * scl + p;
    acc = acc * scl + p * hv;
    m = mn;
  }
  float val = acc / s + b[c];
  if (relu) val = fmaxf(val, 0.f);
  Xout[(size_t)row * H_ + c] = val;
}

// ------- LSTM0 input GEMM (f16 dot2): (96 x 36480) @ (36480 x 1000)^T ------
// SPLITK=60 -> 1920 WGs (15 waves/CU vs 7.5 at SPLITK=30).
__global__ void k_gemm(const float* __restrict__ X, const float* __restrict__ Wih,
                       float* __restrict__ Gpart) {
  __shared__ unsigned Xs[T_][KC / 2 + 1];   // f16 pairs along K
  __shared__ unsigned Ws[BN][KC / 2 + 1];
  int j0 = blockIdx.x * BN;
  int sp = blockIdx.y;
  int tid = threadIdx.x;
  int jj = tid & 7;    // 8 j-groups of 4
  int tt = tid >> 3;   // 16 t-groups of 6
  float acc[6][4] = {};
  int kbeg = sp * (KIN_ / SPLITK);
  int kend = kbeg + (KIN_ / SPLITK);
  for (int k0 = kbeg; k0 < kend; k0 += KC) {
    for (int idx = tid; idx < T_ * (KC / 2); idx += 128) {
      int tr = idx >> 4; int kk = idx & 15;
      const float2 v = *(const float2*)(X + (size_t)tr * KIN_ + k0 + 2 * kk);
      Xs[tr][kk] = packh2(v.x, v.y);
    }
    for (int idx = tid; idx < BN * (KC / 2); idx += 128) {
      int jr = idx >> 4; int kk = idx & 15;
      int j = j0 + jr;
      unsigned v = 0;
      if (j < G4_) {
        const float2 w = *(const float2*)(Wih + (size_t)j * KIN_ + k0 + 2 * kk);
        v = packh2(w.x, w.y);
      }
      Ws[jr][kk] = v;
    }
    __syncthreads();
    for (int kk = 0; kk < KC / 2; ++kk) {
      unsigned xv[6], wv[4];
      #pragma unroll
      for (int r = 0; r < 6; ++r) xv[r] = Xs[tt * 6 + r][kk];
      #pragma unroll
      for (int q = 0; q < 4; ++q) wv[q] = Ws[jj * 4 + q][kk];
      #pragma unroll
      for (int r = 0; r < 6; ++r)
        #pragma unroll
        for (int q = 0; q < 4; ++q)
          acc[r][q] = fdot2u(wv[q], xv[r], acc[r][q]);
    }
    __syncthreads();
  }
  #pragma unroll
  for (int r = 0; r < 6; ++r) {
    int t = tt * 6 + r;
    #pragma unroll
    for (int q = 0; q < 4; ++q) {
      int j = j0 + jj * 4 + q;
      if (j < G4_) Gpart[((size_t)sp * T_ + t) * 1024 + j] = acc[r][q];
    }
  }
}

// G0 reduced with gate-interleaved layout: G0[t*1000 + j*4 + g]
__global__ void k_gred(const float* __restrict__ Gpart, const float* __restrict__ bih,
                       const float* __restrict__ bhh, float* __restrict__ G0) {
  int idx = blockIdx.x * blockDim.x + threadIdx.x;
  if (idx >= T_ * G4_) return;
  int t = idx / G4_; int jg = idx - t * G4_;
  int j = jg >> 2, g = jg & 3;
  int c = g * LH_ + j;                      // gate-major column in Gpart
  float s = bih[c] + bhh[c];
  for (int sp = 0; sp < SPLITK; ++sp) s += Gpart[((size_t)sp * T_ + t) * 1024 + c];
  G0[idx] = s;
}

// ---------------- 8-WG register-resident 2-layer LSTM (R4 structure) -------
// 8 WGs x 512 threads. Wave w owns units 4w..4w+3; each 16-lane quarter-group
// owns one gate row as f16 pairs in VGPRs. Flag barrier per step; G0 for the
// NEXT step prefetched before the barrier (hides its latency).
__global__ void __launch_bounds__(512, 2) k_lstm(
    const float* __restrict__ G0, const float* __restrict__ Whh0,
    const float* __restrict__ Wih1, const float* __restrict__ Whh1,
    const float* __restrict__ bih1, const float* __restrict__ bhh1,
    const float* __restrict__ h0in, const float* __restrict__ c0in,
    unsigned* __restrict__ hp,     // [2 slots][2 layers][128] f16-pairs
    int* __restrict__ flags,       // [8]
    float* __restrict__ ylast) {
  int tid = threadIdx.x;
  int bid = blockIdx.x;
  int wv = bid * 8 + (tid >> 6);   // 0..63
  int lane = tid & 63;
  int qg = lane >> 4;              // gate: 0=i 1=f 2=g 3=o
  int ql = lane & 15;

  unsigned w0[4][8], wx1[4][8], wh1[4][8];
  float bs1[4], c0l[4], c1l[4];
  bool act[4];
  #pragma unroll
  for (int u = 0; u < 4; ++u) {
    int U = wv * 4 + u;
    act[u] = (U < LH_);
    int Uc = act[u] ? U : 0;
    size_t rb = (size_t)(qg * LH_ + Uc) * LH_;
    #pragma unroll
    for (int m = 0; m < 8; ++m) {
      int pi = m * 16 + ql;
      if (act[u] && pi < 125) {
        w0[u][m]  = packh2(Whh0[rb + 2 * pi], Whh0[rb + 2 * pi + 1]);
        wx1[u][m] = packh2(Wih1[rb + 2 * pi], Wih1[rb + 2 * pi + 1]);
        wh1[u][m] = packh2(Whh1[rb + 2 * pi], Whh1[rb + 2 * pi + 1]);
      } else { w0[u][m] = 0; wx1[u][m] = 0; wh1[u][m] = 0; }
    }
    bs1[u] = act[u] ? (bih1[qg * LH_ + Uc] + bhh1[qg * LH_ + Uc]) : 0.f;
    c0l[u] = act[u] ? c0in[Uc] : 0.f;
    c1l[u] = act[u] ? c0in[LH_ + Uc] : 0.f;
  }

  float gpre[4];
  #pragma unroll
  for (int u = 0; u < 4; ++u)
    gpre[u] = act[u] ? G0[0 * G4_ + (wv * 4 + u) * 4 + qg] : 0.f;

  for (int p = 0; p <= T_; ++p) {
    int rs = (p - 1) & 1, wslot = p & 1;
    unsigned x0p[8], h1p[8];
    // x0p = h0[p-1] (= layer0 recurrent input AND layer1 x input)
    if (p == 0) {
      #pragma unroll
      for (int m = 0; m < 8; ++m) {
        int pi = m * 16 + ql;
        x0p[m] = (pi < 125) ? packh2(h0in[2 * pi], h0in[2 * pi + 1]) : 0u;
      }
    } else {
      #pragma unroll
      for (int m = 0; m < 8; ++m)
        x0p[m] = ld_agent_u(&hp[rs * 256 + m * 16 + ql]);
      if (p == 1) {
        #pragma unroll
        for (int m = 0; m < 8; ++m) {
          int pi = m * 16 + ql;
          h1p[m] = (pi < 125) ? packh2(h0in[LH_ + 2 * pi], h0in[LH_ + 2 * pi + 1]) : 0u;
        }
      } else {
        #pragma unroll
        for (int m = 0; m < 8; ++m)
          h1p[m] = ld_agent_u(&hp[rs * 256 + 128 + m * 16 + ql]);
      }
    }

    // ---- layer 0, step p ----
    if (p < T_) {
      float h0new[4];
      #pragma unroll
      for (int u = 0; u < 4; ++u) {
        float s = 0.f;
        #pragma unroll
        for (int m = 0; m < 8; ++m) s = fdot2u(w0[u][m], x0p[m], s);
        s += __shfl_xor(s, 1); s += __shfl_xor(s, 2);
        s += __shfl_xor(s, 4); s += __shfl_xor(s, 8);
        float pre = s + gpre[u];
        float a = (qg == 2) ? ftanh(pre) : fsigm(pre);
        float ai = __shfl(a, ql);
        float af = __shfl(a, 16 + ql);
        float ag = __shfl(a, 32 + ql);
        float ao = __shfl(a, 48 + ql);
        c0l[u] = af * c0l[u] + ai * ag;
        h0new[u] = act[u] ? (ao * ftanh(c0l[u])) : 0.f;
      }
      if (lane == 0) {
        st_agent_u(&hp[wslot * 256 + 2 * wv],     packh2(h0new[0], h0new[1]));
        st_agent_u(&hp[wslot * 256 + 2 * wv + 1], packh2(h0new[2], h0new[3]));
      }
    }
    // ---- layer 1, step p-1 ----
    if (p >= 1) {
      float h1new[4];
      #pragma unroll
      for (int u = 0; u < 4; ++u) {
        float s = 0.f;
        #pragma unroll
        for (int m = 0; m < 8; ++m) s = fdot2u(wx1[u][m], x0p[m], s);
        #pragma unroll
        for (int m = 0; m < 8; ++m) s = fdot2u(wh1[u][m], h1p[m], s);
        s += __shfl_xor(s, 1); s += __shfl_xor(s, 2);
        s += __shfl_xor(s, 4); s += __shfl_xor(s, 8);
        float pre = s + bs1[u];
        float a = (qg == 2) ? ftanh(pre) : fsigm(pre);
        float bi = __shfl(a, ql);
        float bf = __shfl(a, 16 + ql);
        float bg = __shfl(a, 32 + ql);
        float bo = __shfl(a, 48 + ql);
        c1l[u] = bf * c1l[u] + bi * bg;
        h1new[u] = act[u] ? (bo * ftanh(c1l[u])) : 0.f;
      }
      if (p - 1 == T_ - 1 && lane == 0) {
        #pragma unroll
        for (int u = 0; u < 4; ++u)
          if (act[u]) ylast[wv * 4 + u] = h1new[u];
      }
      if (lane == 0) {
        st_agent_u(&hp[wslot * 256 + 128 + 2 * wv],     packh2(h1new[0], h1new[1]));
        st_agent_u(&hp[wslot * 256 + 128 + 2 * wv + 1], packh2(h1new[2], h1new[3]));
      }
    }
    // ---- prefetch next step's G0 (independent of the barrier) ----
    float gnext[4];
    #pragma unroll
    for (int u = 0; u < 4; ++u)
      gnext[u] = (p + 1 < T_ && act[u]) ? G0[(p + 1) * G4_ + (wv * 4 + u) * 4 + qg] : 0.f;
    // ---- fence-free barrier ----
    if (p < T_) {
      __syncthreads();   // implicit vmcnt drain: all sc1 stores acked
      if (tid == 0) {
        asm volatile("s_waitcnt vmcnt(0)" ::: "memory");
        st_agent_i(&flags[bid], p + 1);
      }
      if (tid < 64) {
        int guard = 0;
        for (;;) {
          int f = ld_agent_i(&flags[lane & 7]);
          if (__ballot(f >= p + 1) == ~0ULL) break;
          if (++guard > (1 << 22)) break;   // hang insurance only
          __builtin_amdgcn_s_sleep(1);
        }
      }
      __syncthreads();
    }
    #pragma unroll
    for (int u = 0; u < 4; ++u) gpre[u] = gnext[u];
  }
}

// ---------------- 4 FC heads ----------------------------------------------
__global__ void k_fc(const float* __restrict__ ylast,
                     const float* __restrict__ Wa, const float* __restrict__ ba,
                     const float* __restrict__ Wb, const float* __restrict__ bb,
                     const float* __restrict__ Wc, const float* __restrict__ bc,
                     const float* __restrict__ Wd, const float* __restrict__ bd,
                     float* __restrict__ out) {
  int wg = blockIdx.x * 4 + (threadIdx.x >> 6);
  int lane = threadIdx.x & 63;
  if (wg >= 4 * OUT_) return;
  int head = wg / OUT_, o = wg - head * OUT_;
  const float* W = head == 0 ? Wa : head == 1 ? Wb : head == 2 ? Wc : Wd;
  const float* b = head == 0 ? ba : head == 1 ? bb : head == 2 ? bc : bd;
  float s = 0.f;
  #pragma unroll
  for (int r = 0; r < 4; ++r) {
    int idx = r * 64 + lane;
    if (idx < LH_) s += ylast[idx] * W[(size_t)o * LH_ + idx];
  }
  #pragma unroll
  for (int off = 32; off > 0; off >>= 1) s += __shfl_xor(s, off, 64);
  if (lane == 0) out[wg] = s + b[o];
}

// ---------------- launch ---------------------------------------------------
extern "C" void kernel_launch(void* const* d_in, const int* in_sizes, int n_in,
                              void* d_out, int out_size, void* d_ws, size_t ws_size,
                              hipStream_t stream) {
  const float* nodes = (const float*)d_in[0];
  const int*   ei    = (const int*)d_in[1];
  const float* W1    = (const float*)d_in[3];
  const float* as1   = (const float*)d_in[4];
  const float* ad1   = (const float*)d_in[5];
  const float* b1    = (const float*)d_in[6];
  const float* W2    = (const float*)d_in[7];
  const float* as2   = (const float*)d_in[8];
  const float* ad2   = (const float*)d_in[9];
  const float* b2    = (const float*)d_in[10];
  const float* Wih0  = (const float*)d_in[11];
  const float* Whh0  = (const float*)d_in[12];
  const float* bih0  = (const float*)d_in[13];
  const float* bhh0  = (const float*)d_in[14];
  const float* Wih1  = (const float*)d_in[15];
  const float* Whh1  = (const float*)d_in[16];
  const float* bih1  = (const float*)d_in[17];
  const float* bhh1  = (const float*)d_in[18];
  const float* h0    = (const float*)d_in[19];
  const float* c0    = (const float*)d_in[20];
  const float* fW1   = (const float*)d_in[21];
  const float* fb1   = (const float*)d_in[22];
  const float* fW2   = (const float*)d_in[23];
  const float* fb2   = (const float*)d_in[24];
  const float* fW3   = (const float*)d_in[25];
  const float* fb3   = (const float*)d_in[26];
  const float* fW4   = (const float*)d_in[27];
  const float* fb4   = (const float*)d_in[28];
  float* out = (float*)d_out;

  // workspace layout (bytes). Gpart (23.6 MB, SPLITK=60) overlaps the
  // temporally-dead Hbuf/HS/HD/X1 region: k_gemm runs strictly after k_aggr2.
  const size_t o_Gpart  = 0;          // 60*96*1024*4 = 23,592,960
  const size_t o_H      = 0;          // Hbuf: dead before k_gemm
  const size_t o_HS     = 14008320;
  const size_t o_HD     = 14446080;
  const size_t o_X1     = 14883840;
  const size_t o_X2     = 28892160;   // live during k_gemm: above Gpart end
  const size_t o_counts = 42900480;
  const size_t o_offs   = 43338240;
  const size_t o_cursor = 43776512;
  const size_t o_elist  = 44214272;
  const size_t o_G0     = 52969472;   // 384,000
  const size_t o_hp     = 53353472;   // 2*2*128 uint = 2048
  const size_t o_flags  = 53355520;   // 256
  const size_t o_ylast  = 53355776;   // 1024
  const size_t total    = 53356800;
  if (ws_size < total) return;  // leaves d_out poisoned -> visible failure

  char* ws = (char*)d_ws;
  float*    Gpart  = (float*)(ws + o_Gpart);
  float*    Hbuf   = (float*)(ws + o_H);
  float*    HS     = (float*)(ws + o_HS);
  float*    HD     = (float*)(ws + o_HD);
  float*    X1     = (float*)(ws + o_X1);
  float*    X2     = (float*)(ws + o_X2);
  int*      counts = (int*)(ws + o_counts);
  int*      offs   = (int*)(ws + o_offs);
  int*      cursor = (int*)(ws + o_cursor);
  int*      elist  = (int*)(ws + o_elist);
  float*    G0     = (float*)(ws + o_G0);
  unsigned* hp     = (unsigned*)(ws + o_hp);
  int*      flags  = (int*)(ws + o_flags);
  float*    ylast  = (float*)(ws + o_ylast);

  (void)hipMemsetAsync(counts, 0, (size_t)T_ * N_ * 4, stream);
  (void)hipMemsetAsync(hp, 0, 2048, stream);
  (void)hipMemsetAsync(flags, 0, 256, stream);

  const int rows_grid = (T_ * N_ * H_) / 256;   // 13680
  const int eg = (T_ * E_ + 255) / 256;         // 8550

  // GAT layer 1
  k_feat<<<rows_grid, 256, 0, stream>>>(nodes, W1, as1, ad1, Hbuf, HS, HD, F_);
  k_count<<<eg, 256, 0, stream>>>(ei, counts);
  k_scan<<<T_, 256, 0, stream>>>(counts, offs, cursor);
  k_fill<<<eg, 256, 0, stream>>>(ei, cursor, elist);
  k_aggr<<<rows_grid, 256, 0, stream>>>(Hbuf, HS, HD, offs, elist, b1, X1, 1);
  // GAT layer 2
  k_feat<<<rows_grid, 256, 0, stream>>>(X1, W2, as2, ad2, Hbuf, HS, HD, H_);
  k_aggr<<<rows_grid, 256, 0, stream>>>(Hbuf, HS, HD, offs, elist, b2, X2, 0);
  // LSTM0 input projection (f16 dot2, SPLITK=60)
  k_gemm<<<dim3(32, SPLITK), 128, 0, stream>>>(X2, Wih0, Gpart);
  k_gred<<<(T_ * G4_ + 255) / 256, 256, 0, stream>>>(Gpart, bih0, bhh0, G0);
  // 8-WG register-resident recurrence (R4-verified) + G0 prefetch
  k_lstm<<<8, 512, 0, stream>>>(G0, Whh0, Wih1, Whh1, bih1, bhh1, h0, c0,
                                hp, flags, ylast);
  // FC heads
  k_fc<<<OUT_, 256, 0, stream>>>(ylast, fW1, fb1, fW2, fb2, fW3, fb3, fW4, fb4, out);
}